// Round 8
// baseline (154.353 us; speedup 1.0000x reference)
//
#include <hip/hip_runtime.h>
#include <hip/hip_fp16.h>

// out[b,o] = sum_i x[b,i] * (W[h,i,o] + 0.1*dW[h*ns+s, i, o])
// IN=10, OUT=8.
// Round 8: split tables by precision need.
//   W16[h]  = fp16(W[h])                       4 MB  (hot, ~L2-resident)
//   D8[g]   = fp8_e4m3(0.1*dW[g] * 4096)      32 MB  (cold gather, halved bytes)
// Compute: out = accW + 2^-12 * accD. fp8 decode via v_cvt_pk_f32_fp8.
// x/idx keep nontemporal loads (zero reuse); out uses normal stores.

#define IN_DIM 10
#define OUT_DIM 8
#define ROW 80           // IN_DIM*OUT_DIM
#define D8_SCALE 409.6f  // 0.1 * 4096
#define D8_INV   2.44140625e-4f  // 2^-12

typedef float f2v __attribute__((ext_vector_type(2)));
typedef float f4v __attribute__((ext_vector_type(4)));
typedef unsigned int u4v __attribute__((ext_vector_type(4)));
typedef unsigned int u2v __attribute__((ext_vector_type(2)));

struct alignas(16) H8 { __half2 a, b, c, d; };

// ---- build fp16 W table: thread handles 8 consecutive elements ----
__global__ __launch_bounds__(256) void fd5_build_w(
    const float* __restrict__ W, __half* __restrict__ W16, unsigned total8)
{
    const unsigned t = blockIdx.x * blockDim.x + threadIdx.x;
    if (t >= total8) return;
    const unsigned j = t * 8u;
    const float4* w4 = reinterpret_cast<const float4*>(W + j);
    const float4 a = w4[0], b = w4[1];
    H8 o;
    o.a = __floats2half2_rn(a.x, a.y);
    o.b = __floats2half2_rn(a.z, a.w);
    o.c = __floats2half2_rn(b.x, b.y);
    o.d = __floats2half2_rn(b.z, b.w);
    *reinterpret_cast<H8*>(W16 + j) = o;
}

// ---- build fp8 dW table: thread handles 8 consecutive elements ----
__global__ __launch_bounds__(256) void fd5_build_d(
    const float* __restrict__ dW, unsigned char* __restrict__ D8, unsigned total8)
{
    const unsigned t = blockIdx.x * blockDim.x + threadIdx.x;
    if (t >= total8) return;
    const unsigned j = t * 8u;
    const float4* d4 = reinterpret_cast<const float4*>(dW + j);
    const float4 a = d4[0], b = d4[1];
    int v0 = 0, v1 = 0;
    v0 = __builtin_amdgcn_cvt_pk_fp8_f32(a.x * D8_SCALE, a.y * D8_SCALE, v0, false);
    v0 = __builtin_amdgcn_cvt_pk_fp8_f32(a.z * D8_SCALE, a.w * D8_SCALE, v0, true);
    v1 = __builtin_amdgcn_cvt_pk_fp8_f32(b.x * D8_SCALE, b.y * D8_SCALE, v1, false);
    v1 = __builtin_amdgcn_cvt_pk_fp8_f32(b.z * D8_SCALE, b.w * D8_SCALE, v1, true);
    u2v o; o[0] = (unsigned)v0; o[1] = (unsigned)v1;
    *reinterpret_cast<u2v*>(D8 + j) = o;  // 8B store, j%8==0 -> aligned
}

__device__ __forceinline__ void fd5_acc_w(float xi, u4v w, float* acc)
{
#pragma unroll
    for (int q = 0; q < 4; ++q) {
        unsigned u = w[q];
        const __half2 hh = *reinterpret_cast<const __half2*>(&u);
        const float2 f = __half22float2(hh);
        acc[2 * q]     = fmaf(xi, f.x, acc[2 * q]);
        acc[2 * q + 1] = fmaf(xi, f.y, acc[2 * q + 1]);
    }
}

// one 16B chunk of D8 = 16 fp8 = rows {2q, 2q+1} (8 outputs each)
__device__ __forceinline__ void fd5_acc_d(float xi0, float xi1, u4v cc, float* acc)
{
#pragma unroll
    for (int half = 0; half < 2; ++half) {           // half 0: row 2q (xi0), 1: row 2q+1 (xi1)
        const float xi = half ? xi1 : xi0;
#pragma unroll
        for (int p = 0; p < 2; ++p) {                // p: outputs 0..3 / 4..7
            const int u = half * 2 + p;
            const f2v lo = __builtin_amdgcn_cvt_pk_f32_fp8((int)cc[u], false);
            const f2v hi = __builtin_amdgcn_cvt_pk_f32_fp8((int)cc[u], true);
            acc[4 * p + 0] = fmaf(xi, lo[0], acc[4 * p + 0]);
            acc[4 * p + 1] = fmaf(xi, lo[1], acc[4 * p + 1]);
            acc[4 * p + 2] = fmaf(xi, hi[0], acc[4 * p + 2]);
            acc[4 * p + 3] = fmaf(xi, hi[1], acc[4 * p + 3]);
        }
    }
}

// ---- main: one lane per token ----
__global__ __launch_bounds__(256) void fd5_main(
    const float* __restrict__ x, const __half* __restrict__ W16,
    const unsigned char* __restrict__ D8,
    const int* __restrict__ head_ix, const int* __restrict__ split_ix,
    float* __restrict__ out, int B, int NS)
{
    const int t = blockIdx.x * blockDim.x + threadIdx.x;
    if (t >= B) return;

    const int h = __builtin_nontemporal_load(head_ix + t);
    const int s = __builtin_nontemporal_load(split_ix + t);
    const size_t g = (size_t)h * (size_t)NS + (size_t)s;

    const u4v* __restrict__ wrow = reinterpret_cast<const u4v*>(W16 + (size_t)h * ROW);
    const u4v* __restrict__ drow = reinterpret_cast<const u4v*>(D8 + g * ROW);

    // issue the cold gather first (5x16B), then the hot W row (10x16B)
    const u4v d0 = drow[0], d1 = drow[1], d2 = drow[2], d3 = drow[3], d4 = drow[4];
    const u4v w0 = wrow[0], w1 = wrow[1], w2 = wrow[2], w3 = wrow[3], w4 = wrow[4];
    const u4v w5 = wrow[5], w6 = wrow[6], w7 = wrow[7], w8 = wrow[8], w9 = wrow[9];

    const f2v* __restrict__ x2 = reinterpret_cast<const f2v*>(x + (size_t)t * 10);
    const f2v p0 = __builtin_nontemporal_load(x2 + 0);
    const f2v p1 = __builtin_nontemporal_load(x2 + 1);
    const f2v p2 = __builtin_nontemporal_load(x2 + 2);
    const f2v p3 = __builtin_nontemporal_load(x2 + 3);
    const f2v p4 = __builtin_nontemporal_load(x2 + 4);

    float accW[8] = {0,0,0,0,0,0,0,0};
    float accD[8] = {0,0,0,0,0,0,0,0};

    fd5_acc_d(p0[0], p0[1], d0, accD);
    fd5_acc_d(p1[0], p1[1], d1, accD);
    fd5_acc_d(p2[0], p2[1], d2, accD);
    fd5_acc_d(p3[0], p3[1], d3, accD);
    fd5_acc_d(p4[0], p4[1], d4, accD);

    fd5_acc_w(p0[0], w0, accW);
    fd5_acc_w(p0[1], w1, accW);
    fd5_acc_w(p1[0], w2, accW);
    fd5_acc_w(p1[1], w3, accW);
    fd5_acc_w(p2[0], w4, accW);
    fd5_acc_w(p2[1], w5, accW);
    fd5_acc_w(p3[0], w6, accW);
    fd5_acc_w(p3[1], w7, accW);
    fd5_acc_w(p4[0], w8, accW);
    fd5_acc_w(p4[1], w9, accW);

    f4v o0, o1;
#pragma unroll
    for (int o = 0; o < 4; ++o) o0[o] = fmaf(D8_INV, accD[o], accW[o]);
#pragma unroll
    for (int o = 0; o < 4; ++o) o1[o] = fmaf(D8_INV, accD[4 + o], accW[4 + o]);

    f4v* __restrict__ op = reinterpret_cast<f4v*>(out + (size_t)t * 8);
    op[0] = o0;
    op[1] = o1;
}

// Fallback (fp32 direct) if workspace can't hold the tables.
__global__ __launch_bounds__(256) void fd5_direct(
    const float* __restrict__ x, const float* __restrict__ W, const float* __restrict__ dW,
    const int* __restrict__ head_ix, const int* __restrict__ split_ix,
    const int* __restrict__ nsp, float* __restrict__ out, int B)
{
    const int gid = blockIdx.x * blockDim.x + threadIdx.x;
    const int t = gid >> 1;
    const int hf = gid & 1;
    if (t >= B) return;
    const int ns = nsp[0];
    const int h = head_ix[t];
    const float* wrow = W + (size_t)h * ROW + (size_t)hf * 4;
    const float* drow = dW + ((size_t)h * ns + split_ix[t]) * ROW + (size_t)hf * 4;
    const float2* x2 = reinterpret_cast<const float2*>(x + (size_t)t * 10);
    const float2 p0 = x2[0], p1 = x2[1], p2 = x2[2], p3 = x2[3], p4 = x2[4];
    const float xv[10] = {p0.x, p0.y, p1.x, p1.y, p2.x, p2.y, p3.x, p3.y, p4.x, p4.y};
    float4 acc = make_float4(0.f, 0.f, 0.f, 0.f);
#pragma unroll
    for (int i = 0; i < 10; ++i) {
        const float4 w4 = *reinterpret_cast<const float4*>(wrow + i * 8);
        const float4 d4 = *reinterpret_cast<const float4*>(drow + i * 8);
        const float xi = xv[i], xs = 0.1f * xi;
        acc.x = fmaf(xi, w4.x, fmaf(xs, d4.x, acc.x));
        acc.y = fmaf(xi, w4.y, fmaf(xs, d4.y, acc.y));
        acc.z = fmaf(xi, w4.z, fmaf(xs, d4.z, acc.z));
        acc.w = fmaf(xi, w4.w, fmaf(xs, d4.w, acc.w));
    }
    *reinterpret_cast<float4*>(out + (size_t)t * 8 + (size_t)hf * 4) = acc;
}

extern "C" void kernel_launch(void* const* d_in, const int* in_sizes, int n_in,
                              void* d_out, int out_size, void* d_ws, size_t ws_size,
                              hipStream_t stream) {
    const float* x        = (const float*)d_in[0];
    const float* W        = (const float*)d_in[1];
    const float* dW       = (const float*)d_in[2];
    const int*   head_ix  = (const int*)d_in[3];
    const int*   split_ix = (const int*)d_in[4];
    const int*   nsp      = (const int*)d_in[5];
    float* out = (float*)d_out;

    const int B  = in_sizes[0] / IN_DIM;        // x  [B, 10]
    const int NH = in_sizes[1] / ROW;           // W  [NH, 10, 8]
    const int NS = in_sizes[2] / in_sizes[1];   // dW [NH*NS, 10, 8]

    const int block = 256;

    const size_t w_elems = (size_t)NH * ROW;         // fp16 elements
    const size_t d_elems = (size_t)NH * NS * ROW;    // fp8 elements
    const size_t w_bytes = (w_elems * sizeof(__half) + 255) & ~(size_t)255;
    const size_t need    = w_bytes + d_elems + 256;

    if (d_ws == nullptr || ws_size < need) {
        const long long lanes = 2LL * B;
        const int fgrid = (int)((lanes + block - 1) / block);
        fd5_direct<<<fgrid, block, 0, stream>>>(x, W, dW, head_ix, split_ix, nsp, out, B);
        return;
    }

    char* base = (char*)(((uintptr_t)d_ws + 255) & ~(uintptr_t)255);
    __half* W16       = (__half*)base;
    unsigned char* D8 = (unsigned char*)(base + w_bytes);

    const unsigned w8 = (unsigned)(w_elems / 8);
    const unsigned d8 = (unsigned)(d_elems / 8);
    fd5_build_w<<<(int)((w8 + block - 1) / block), block, 0, stream>>>(W, W16, w8);
    fd5_build_d<<<(int)((d8 + block - 1) / block), block, 0, stream>>>(dW, D8, d8);

    const int cgrid = (B + block - 1) / block;
    fd5_main<<<cgrid, block, 0, stream>>>(x, W16, D8, head_ix, split_ix, out, B, NS);
}